// Round 2
// baseline (670.342 us; speedup 1.0000x reference)
//
#include <hip/hip_runtime.h>

// AutoCorrelation (Autoformer): B=4,N=207,L=96,H=8,E=64, float32 in/out.
// One block per (b,n,h); thread = (e = tid>>2, tau-block = tid&3 -> 24 lags).
// corr[tau] = sum_t q[t]*k[(t-tau)%96]; K,V tiles in LDS; Q streamed from global.

namespace {
constexpr int Lx = 96;
constexpr int Hx = 8;
constexpr int Ex = 64;
constexpr int HE = Hx * Ex;               // 512
constexpr int NBH = 4 * 207 * Hx;         // 6624 blocks
constexpr long OUT1 = 4L * 207 * Lx * Hx * Ex;  // 40697856 elements per output
constexpr int KP = 66;  // LDS row stride (floats): float2-aligned, 2-way max bank alias
constexpr int VP = 66;
}

__device__ __forceinline__ void sel_max(float av, int ai, float bv, int bi,
                                        float& ov, int& oi) {
  bool ta = (av > bv) || ((av == bv) && (ai < bi));
  ov = ta ? av : bv;
  oi = ta ? ai : bi;
}

__device__ __forceinline__ void cswap_desc(float& xv, int& xi, float& yv, int& yi) {
  bool sw = (yv > xv) || ((yv == xv) && (yi < xi));
  float nxv = sw ? yv : xv, nyv = sw ? xv : yv;
  int nxi = sw ? yi : xi, nyi = sw ? xi : yi;
  xv = nxv; yv = nyv; xi = nxi; yi = nyi;
}

__global__ __launch_bounds__(256, 3) void autocorr_kernel(
    const float* __restrict__ qg,
    const float* __restrict__ kg,
    const float* __restrict__ vg,
    float* __restrict__ outV,
    float* __restrict__ outC) {
  __shared__ __align__(16) float sK[Lx * KP];
  __shared__ __align__(16) float sV[Lx * VP];

  const int tid = threadIdx.x;
  const int bid = blockIdx.x;
  const int bn = bid >> 3;          // (b*N+n) in [0,828)
  const int h = bid & 7;
  const int base = bn * (Lx * HE) + h * Ex;

  // ---- stage k,v into LDS: rows of 64 floats, coalesced float4 global reads ----
#pragma unroll
  for (int i = 0; i < 6; ++i) {
    int f = i * 256 + tid;          // 1536 float4 chunks per array
    int t = f >> 4;
    int e4 = (f & 15) << 2;
    int g = base + t * HE + e4;
    float4 kv = *reinterpret_cast<const float4*>(kg + g);
    float4 vv = *reinterpret_cast<const float4*>(vg + g);
    int s = t * KP + e4;            // byte addr (s*4): stride 264 -> 8B aligned
    *reinterpret_cast<float2*>(sK + s)     = make_float2(kv.x, kv.y);
    *reinterpret_cast<float2*>(sK + s + 2) = make_float2(kv.z, kv.w);
    *reinterpret_cast<float2*>(sV + s)     = make_float2(vv.x, vv.y);
    *reinterpret_cast<float2*>(sV + s + 2) = make_float2(vv.z, vv.w);
  }
  __syncthreads();

  const int e = tid >> 2;
  const int tb = tid & 3;
  const int tau0 = tb * 24;

  float acc[24];
#pragma unroll
  for (int j = 0; j < 24; ++j) acc[j] = 0.0f;

  const float* qp = qg + base + e;
  const float* kcol = sK + e;

  // kvp[m] = k[(24*(c-1-tb) + m) mod 96]; rows are 24-aligned so no mid-chunk wrap.
  float kvp[24];
  {
    int r0 = ((-1 - tb) & 3) * 24;
#pragma unroll
    for (int m = 0; m < 24; ++m) kvp[m] = kcol[(r0 + m) * KP];
  }

#pragma unroll 1
  for (int c = 0; c < 4; ++c) {
    int r0 = ((c - tb) & 3) * 24;
    float kv[24], qv[24];
#pragma unroll
    for (int tt = 0; tt < 24; ++tt) {
      kv[tt] = kcol[(r0 + tt) * KP];          // k[(24c + tt - tau0) mod 96]
      qv[tt] = qp[(c * 24 + tt) * HE];        // q[24c + tt]
    }
#pragma unroll
    for (int tt = 0; tt < 24; ++tt) {
      float qt = qv[tt];
#pragma unroll
      for (int j = 0; j <= tt; ++j) acc[j] += qt * kv[tt - j];
#pragma unroll
      for (int j = tt + 1; j < 24; ++j) acc[j] += qt * kvp[tt - j + 24];
    }
#pragma unroll
    for (int m = 0; m < 24; ++m) kvp[m] = kv[m];
  }
  // acc[j] == corr[tau0 + j]

  // ---- local top-4 (value desc, index asc on ties: strict > keeps earliest) ----
  float v0 = -__builtin_inff(), v1 = v0, v2 = v0, v3 = v0;
  int i0 = 0, i1 = 0, i2 = 0, i3 = 0;
#pragma unroll
  for (int j = 0; j < 24; ++j) {
    float nv = acc[j];
    int ni = tau0 + j;
    if (nv > v0) { v3 = v2; i3 = i2; v2 = v1; i2 = i1; v1 = v0; i1 = i0; v0 = nv; i0 = ni; }
    else if (nv > v1) { v3 = v2; i3 = i2; v2 = v1; i2 = i1; v1 = nv; i1 = ni; }
    else if (nv > v2) { v3 = v2; i3 = i2; v2 = nv; i2 = ni; }
    else if (nv > v3) { v3 = nv; i3 = ni; }
  }

  // ---- merge across the 4 tau-block lanes (xor 1, then 2): bitonic top-4 ----
#pragma unroll
  for (int m = 1; m <= 2; m <<= 1) {
    float b0 = __shfl_xor(v0, m, 64);
    float b1 = __shfl_xor(v1, m, 64);
    float b2 = __shfl_xor(v2, m, 64);
    float b3 = __shfl_xor(v3, m, 64);
    int j0 = __shfl_xor(i0, m, 64);
    int j1 = __shfl_xor(i1, m, 64);
    int j2 = __shfl_xor(i2, m, 64);
    int j3 = __shfl_xor(i3, m, 64);
    float t0, t1, t2, t3;
    int u0, u1, u2, u3;
    sel_max(v0, i0, b3, j3, t0, u0);   // bitonic merge: max(x_i, x_{7-i})
    sel_max(v1, i1, b2, j2, t1, u1);
    sel_max(v2, i2, b1, j1, t2, u2);
    sel_max(v3, i3, b0, j0, t3, u3);
    cswap_desc(t0, u0, t2, u2);        // sort bitonic-4 descending (stable by index)
    cswap_desc(t1, u1, t3, u3);
    cswap_desc(t0, u0, t1, u1);
    cswap_desc(t2, u2, t3, u3);
    v0 = t0; v1 = t1; v2 = t2; v3 = t3;
    i0 = u0; i1 = u1; i2 = u2; i3 = u3;
  }

  // ---- softmax over the sorted top-4 values ----
  float w1 = __expf(v1 - v0);
  float w2 = __expf(v2 - v0);
  float w3 = __expf(v3 - v0);
  float inv = 1.0f / (1.0f + w1 + w2 + w3);
  float w0 = inv;
  w1 *= inv; w2 *= inv; w3 *= inv;

  // ---- write corr (from acc) and V (weighted circular gather of v) ----
#pragma unroll
  for (int j = 0; j < 24; ++j) {
    int t = tau0 + j;
    int g = base + t * HE + e;
    outC[g] = acc[j];
    int t0 = t + i0; if (t0 >= 96) t0 -= 96;
    int t1 = t + i1; if (t1 >= 96) t1 -= 96;
    int t2 = t + i2; if (t2 >= 96) t2 -= 96;
    int t3 = t + i3; if (t3 >= 96) t3 -= 96;
    float r = w0 * sV[t0 * VP + e];
    r += w1 * sV[t1 * VP + e];
    r += w2 * sV[t2 * VP + e];
    r += w3 * sV[t3 * VP + e];
    outV[g] = r;
  }
}

extern "C" void kernel_launch(void* const* d_in, const int* in_sizes, int n_in,
                              void* d_out, int out_size, void* d_ws, size_t ws_size,
                              hipStream_t stream) {
  const float* q = (const float*)d_in[0];
  const float* k = (const float*)d_in[1];
  const float* v = (const float*)d_in[2];
  // d_in[3] = attn_mask (scalar, unused)
  float* out = (float*)d_out;               // [V | corr], each OUT1 elements
  autocorr_kernel<<<dim3(NBH), dim3(256), 0, stream>>>(q, k, v, out, out + OUT1);
}